// Round 6
// baseline (650.307 us; speedup 1.0000x reference)
//
#include <hip/hip_runtime.h>
#include <cmath>

// GAT layer: N=4096 nodes, FIN=128, F=64 per head, H=8 heads.
// Pipeline:
//   k0: pack A -> 64-bit masks (ballot); swizzle W, X (fp32->f16) into
//       MFMA fragment order.
//   k1: feats = X @ W[h] via f16 MFMA; factored exps es/esn/et/etn (f16);
//       feats stored f16 in MFMA-B-swizzled order.
//   k2: P[n,m] = mask * max(es_n*et_m, esn_n*etn_m); PV via
//       v_mfma_f32_16x16x32_f16; denom via v_dot2.
//       v6: rounds 2-5 showed four different inner loops all pinned at
//       ~46us with ~60% no-issue -> all-wave convoy stall; only the
//       occupancy knob ever moved time (2->4 waves/SIMD = -3us). v5's
//       zero-LDS loop measured VGPR=60 -> fits the 64-reg budget of
//       8 waves/SIMD. So: 512 thr = 8 waves/block, each wave 8 cts,
//       grid 1024 -> 4 blocks/CU, 32 waves/CU (FULL device TLP).
//       LB(512,8). Inner loop unchanged (in-register masks, 2-deep
//       B-frag pipeline, sched_barrier fences). 8-way epilogue reduce.

#define NN 4096
#define FIN 128
#define FF 64
#define HH 8

typedef _Float16 h2 __attribute__((ext_vector_type(2)));
typedef _Float16 h4 __attribute__((ext_vector_type(4)));
typedef _Float16 h8 __attribute__((ext_vector_type(8)));
typedef float f32x2 __attribute__((ext_vector_type(2)));
typedef float f32x4 __attribute__((ext_vector_type(4)));

union H8 {
  h8 v;
  h2 p[4];
};
union U2 {
  h2 h;
  unsigned u;
};

static __device__ __forceinline__ float dot2acc(h2 a, float c) {
#if __has_builtin(__builtin_amdgcn_fdot2)
  return __builtin_amdgcn_fdot2(a, (h2){(_Float16)1.f, (_Float16)1.f}, c,
                                false);
#else
  return c + (float)a[0] + (float)a[1];
#endif
}

// bits j, j+1 of w -> packed 16-bit masks {bit j ? 0xFFFF : 0, bit j+1 ...}
static __device__ __forceinline__ unsigned mask2(unsigned w, int j) {
#if __has_builtin(__builtin_amdgcn_sbfe) && __has_builtin(__builtin_amdgcn_perm)
  int lo = __builtin_amdgcn_sbfe((int)w, j, 1);       // 0 or 0xFFFFFFFF
  int hi = __builtin_amdgcn_sbfe((int)w, j + 1, 1);
  return __builtin_amdgcn_perm((unsigned)hi, (unsigned)lo, 0x05040100u);
#else
  int lo = ((int)(w << (31 - j))) >> 31;
  int hi = ((int)(w << (30 - j))) >> 31;
  return ((unsigned)lo & 0xFFFFu) | ((unsigned)hi << 16);
#endif
}

// ---------------------------------------------------------------- kernel 0
__global__ __launch_bounds__(256) void pack_kernel(
    const int* __restrict__ A, const float* __restrict__ W,
    const float* __restrict__ X, unsigned long long* __restrict__ bits,
    _Float16* __restrict__ Wsw, _Float16* __restrict__ Xsw) {
  const int b = blockIdx.x;
  const int tid = threadIdx.x;
  const int wave = tid >> 6, lane = tid & 63;
  if (b < NN) {
    __shared__ int ldsT[4][4][256];  // [wave][iter][col-within-group]
    const int* ar = A + (size_t)b * NN;
    int4 v[4];
#pragma unroll
    for (int it = 0; it < 4; ++it) {
      const int g = wave * 4 + it;  // 256-col group
      v[it] = *(const int4*)(ar + g * 256 + lane * 4);
    }
#pragma unroll
    for (int it = 0; it < 4; ++it) *(int4*)&ldsT[wave][it][lane * 4] = v[it];
    unsigned long long* br = bits + ((size_t)b << 6);
#pragma unroll
    for (int it = 0; it < 4; ++it) {
      const int g = wave * 4 + it;
      int w0 = ldsT[wave][it][0 * 64 + lane];
      int w1 = ldsT[wave][it][1 * 64 + lane];
      int w2 = ldsT[wave][it][2 * 64 + lane];
      int w3 = ldsT[wave][it][3 * 64 + lane];
      unsigned long long m0 = __ballot(w0 != 0);
      unsigned long long m1 = __ballot(w1 != 0);
      unsigned long long m2 = __ballot(w2 != 0);
      unsigned long long m3 = __ballot(w3 != 0);
      if (lane == 0) {
        ulonglong2 p0 = {m0, m1}, p1 = {m2, m3};
        *(ulonglong2*)(br + g * 4 + 0) = p0;
        *(ulonglong2*)(br + g * 4 + 2) = p1;
      }
    }
  } else if (b < NN + 2) {
    const int h0 = (b - NN) * 4;
    for (int h = h0; h < h0 + 4; ++h) {
      for (int c = tid; c < 1024; c += 256) {  // (kt, nb, lane)
        int ln = c & 63, nb = (c >> 6) & 3, kt = c >> 8;
        int f = nb * 16 + (ln & 15);
        int k0 = kt * 32 + (ln >> 4) * 8;
        h8 v;
#pragma unroll
        for (int j = 0; j < 8; ++j)
          v[j] = (_Float16)W[((size_t)(h * FIN) + k0 + j) * FF + f];
        *(h8*)(Wsw + ((size_t)(((h * 4 + kt) * 4 + nb) * 64 + ln)) * 8) = v;
      }
    }
  } else {
    const int tile = (b - NN - 2) * 4 + wave;  // 16-row tile, 0..255
    const int l16 = lane & 15, quad = lane >> 4;
    const float* xr = X + (size_t)(tile * 16 + l16) * FIN;
#pragma unroll
    for (int kt = 0; kt < 4; ++kt) {
      int k0 = kt * 32 + quad * 8;
      f32x4 x0 = *(const f32x4*)(xr + k0);
      f32x4 x1 = *(const f32x4*)(xr + k0 + 4);
      h8 v = {(_Float16)x0[0], (_Float16)x0[1], (_Float16)x0[2],
              (_Float16)x0[3], (_Float16)x1[0], (_Float16)x1[1],
              (_Float16)x1[2], (_Float16)x1[3]};
      *(h8*)(Xsw + ((size_t)((tile * 4 + kt) * 64 + lane)) * 8) = v;
    }
  }
}

// ---------------------------------------------------------------- kernel 1
__global__ __launch_bounds__(256) void feats_kernel(
    const _Float16* __restrict__ Xsw, const _Float16* __restrict__ Wsw,
    const float* __restrict__ a_self, const float* __restrict__ a_neigh,
    _Float16* __restrict__ feats_sw, _Float16* __restrict__ es_h,
    _Float16* __restrict__ esn_h, _Float16* __restrict__ et_h,
    _Float16* __restrict__ etn_h) {
  const int h = blockIdx.y;
  const int tid = threadIdx.x, wave = tid >> 6, lane = tid & 63;
  const int l16 = lane & 15, quad = lane >> 4;
  const int rt = blockIdx.x * 4 + wave;  // 16-row tile
  const int r0 = rt * 16;

  f32x4 acc[4];
#pragma unroll
  for (int nb = 0; nb < 4; ++nb) acc[nb] = (f32x4){0.f, 0.f, 0.f, 0.f};

  const _Float16* xp = Xsw + ((size_t)(rt * 4) * 64 + lane) * 8;
  const _Float16* wp = Wsw + ((size_t)(h * 16) * 64 + lane) * 8;
  h8 Af[4];
#pragma unroll
  for (int kt = 0; kt < 4; ++kt) Af[kt] = *(const h8*)(xp + kt * 512);
#pragma unroll
  for (int kt = 0; kt < 4; ++kt)
#pragma unroll
    for (int nb = 0; nb < 4; ++nb) {
      h8 Bf = *(const h8*)(wp + (kt * 4 + nb) * 512);
      acc[nb] = __builtin_amdgcn_mfma_f32_16x16x32_f16(Af[kt], Bf, acc[nb], 0, 0, 0);
    }

  // s_self/s_neigh dots (fp32) -> factored exponentials (f16)
  float as[4], an[4];
#pragma unroll
  for (int nb = 0; nb < 4; ++nb) {
    as[nb] = a_self[h * FF + nb * 16 + l16];
    an[nb] = a_neigh[h * FF + nb * 16 + l16];
  }
#pragma unroll
  for (int r = 0; r < 4; ++r) {
    float ps = acc[0][r] * as[0] + acc[1][r] * as[1] + acc[2][r] * as[2] +
               acc[3][r] * as[3];
    float pn = acc[0][r] * an[0] + acc[1][r] * an[1] + acc[2][r] * an[2] +
               acc[3][r] * an[3];
#pragma unroll
    for (int m = 1; m <= 8; m <<= 1) {
      ps += __shfl_xor(ps, m, 64);
      pn += __shfl_xor(pn, m, 64);
    }
    if (l16 == 0) {
      int node = h * NN + r0 + quad * 4 + r;
      es_h[node] = (_Float16)__expf(ps - 2.0f);
      esn_h[node] = (_Float16)__expf(0.2f * ps - 2.0f);
      et_h[node] = (_Float16)__expf(pn - 2.0f);
      etn_h[node] = (_Float16)__expf(0.2f * pn - 2.0f);
    }
  }

  // swizzled f16 store (MFMA B-fragment order). node = r0 + quad*4 + r.
  const int kb = r0 >> 5;
  const int quadA = ((r0 >> 4) & 1) * 2 + (quad >> 1);
  const int jbase = (quad & 1) << 2;
#pragma unroll
  for (int nb = 0; nb < 4; ++nb) {
    h4 v = {(_Float16)acc[nb][0], (_Float16)acc[nb][1], (_Float16)acc[nb][2],
            (_Float16)acc[nb][3]};
    size_t off = ((size_t)((h * 128 + kb) * 4 + nb) << 9) +
                 ((quadA * 16 + l16) << 3) + jbase;
    *(h4*)(feats_sw + off) = v;
  }
}

// ---------------------------------------------------------------- kernel 2
// grid 1024 = rb*8 + h. 32 rows/block, 512 thr = 8 waves; wave owns both
// row-groups, 8 of 64 column tiles (ct = wave + 8*it). 4 blocks/CU ->
// 32 waves/CU = 8/SIMD (full TLP). 2-deep B-frag register pipeline
// (sched_barrier fences); SGPR-base + uint32 voffset addressing; NO LDS
// in main loop (in-register sbfe/perm masks). LB(512,8) pins 64-VGPR cap
// (v5 measured 60).
__global__ __launch_bounds__(512, 8) void attn_kernel(
    const unsigned long long* __restrict__ Abits,
    const _Float16* __restrict__ feats_sw, const _Float16* __restrict__ es_h,
    const _Float16* __restrict__ esn_h, const _Float16* __restrict__ et_h,
    const _Float16* __restrict__ etn_h, const float* __restrict__ bias,
    float* __restrict__ out) {
  const int bid = blockIdx.x;
  const int h = bid & 7, n0 = (bid >> 3) << 5;  // 32 rows per block
  const int tid = threadIdx.x, wave = tid >> 6, lane = tid & 63;
  const int l16 = lane & 15, quad = lane >> 4;
  const int shq = quad << 3;

  __shared__ float accL[8][16][66];  // 33.8 KB
  __shared__ float denL[8][32];      // 1 KB

  h2 esp[2], esnp[2];
#pragma unroll
  for (int rg = 0; rg < 2; ++rg) {
    _Float16 e = es_h[h * NN + n0 + rg * 16 + l16];
    _Float16 en = esn_h[h * NN + n0 + rg * 16 + l16];
    esp[rg] = (h2){e, e};
    esnp[rg] = (h2){en, en};
  }

  f32x4 acc[2][4];
  float dsA[2] = {0.f, 0.f}, dsB[2] = {0.f, 0.f};
#pragma unroll
  for (int rg = 0; rg < 2; ++rg)
#pragma unroll
    for (int nb = 0; nb < 4; ++nb) acc[rg][nb] = (f32x4){0.f, 0.f, 0.f, 0.f};

  // ---- scalar bases (uniform -> SGPR) + per-lane 32-bit voffsets ----
  const char* sF0 = (const char*)feats_sw + ((size_t)h << 19);  // h*512KB
  const char* sF1 = sF0 + 4096;                                 // kf=1 half
  const char* sE = (const char*)et_h + (h << 13);
  const char* sEN = (const char*)etn_h + (h << 13);
  const char* sB0 = (const char*)Abits + ((size_t)n0 << 9);  // rg=0 rows
  const char* sB1 = sB0 + 8192;                              // rg=1 rows

  unsigned offF = (lane << 4) + (wave << 13);  // lane*16 + ct*8192
  unsigned offE = (quad << 4) + (wave << 7);   // quad*16 + ct*128
  unsigned offB = (l16 << 9) + (wave << 3);    // row(l16)*512 + ct*8

#define COMPUTE_KF(w0_, w1_, Bq0, Bq1, Bq2, Bq3, ETu, ETNu)                   \
  do {                                                                        \
    const unsigned wl_[2] = {w0_, w1_};                                       \
    _Pragma("unroll") for (int rg = 0; rg < 2; ++rg) {                        \
      const unsigned ws_ = wl_[rg] >> shq;                                    \
      H8 P_;                                                                  \
      _Pragma("unroll") for (int p = 0; p < 4; ++p) {                         \
        h2 a_ = esp[rg] * ETu.p[p];                                           \
        h2 b_ = esnp[rg] * ETNu.p[p];                                         \
        h2 r_ = __builtin_elementwise_max(a_, b_);                            \
        U2 u_;                                                                \
        u_.h = r_;                                                            \
        u_.u &= mask2(ws_, 2 * p);                                            \
        P_.p[p] = u_.h;                                                       \
        if (p & 1)                                                            \
          dsB[rg] = dot2acc(u_.h, dsB[rg]);                                   \
        else                                                                  \
          dsA[rg] = dot2acc(u_.h, dsA[rg]);                                   \
      }                                                                       \
      acc[rg][0] = __builtin_amdgcn_mfma_f32_16x16x32_f16(P_.v, Bq0,          \
                                                          acc[rg][0], 0, 0,   \
                                                          0);                 \
      acc[rg][1] = __builtin_amdgcn_mfma_f32_16x16x32_f16(P_.v, Bq1,          \
                                                          acc[rg][1], 0, 0,   \
                                                          0);                 \
      acc[rg][2] = __builtin_amdgcn_mfma_f32_16x16x32_f16(P_.v, Bq2,          \
                                                          acc[rg][2], 0, 0,   \
                                                          0);                 \
      acc[rg][3] = __builtin_amdgcn_mfma_f32_16x16x32_f16(P_.v, Bq3,          \
                                                          acc[rg][3], 0, 0,   \
                                                          0);                 \
    }                                                                         \
  } while (0)

  // prologue: bits(ct0), ET/ETN(ct0, both kf), BA(ct0, kf0)
  uint2 bitsC0 = *(const uint2*)(sB0 + offB);
  uint2 bitsC1 = *(const uint2*)(sB1 + offB);
  H8 ET0, ET1, ETN0, ETN1;
  ET0.v = *(const h8*)(sE + offE);
  ET1.v = *(const h8*)(sE + offE + 64);
  ETN0.v = *(const h8*)(sEN + offE);
  ETN1.v = *(const h8*)(sEN + offE + 64);
  h8 BA0 = *(const h8*)(sF0 + offF);
  h8 BA1 = *(const h8*)(sF0 + offF + 1024);
  h8 BA2 = *(const h8*)(sF0 + offF + 2048);
  h8 BA3 = *(const h8*)(sF0 + offF + 3072);

  for (int it = 0; it < 8; ++it) {
    const unsigned offFn = offF + 65536;  // ct += 8
    const unsigned offEn = offE + 1024;
    const unsigned offBn = offB + 64;

    // issue kf=1 B loads (current ct) + next bits; pin above kf0 compute
    h8 BB0 = *(const h8*)(sF1 + offF);
    h8 BB1 = *(const h8*)(sF1 + offF + 1024);
    h8 BB2 = *(const h8*)(sF1 + offF + 2048);
    h8 BB3 = *(const h8*)(sF1 + offF + 3072);
    uint2 bitsN0 = *(const uint2*)(sB0 + offBn);
    uint2 bitsN1 = *(const uint2*)(sB1 + offBn);
    __builtin_amdgcn_sched_barrier(0);

    // ---- kf = 0 ---- (uses BA, ET0/ETN0 — loaded one phase ago)
    COMPUTE_KF(bitsC0.x, bitsC1.x, BA0, BA1, BA2, BA3, ET0, ETN0);
    __builtin_amdgcn_sched_barrier(0);

    // ET0/ETN0 & BA dead: issue next-ct kf=0 loads; pin above kf1 compute
    ET0.v = *(const h8*)(sE + offEn);
    ETN0.v = *(const h8*)(sEN + offEn);
    BA0 = *(const h8*)(sF0 + offFn);
    BA1 = *(const h8*)(sF0 + offFn + 1024);
    BA2 = *(const h8*)(sF0 + offFn + 2048);
    BA3 = *(const h8*)(sF0 + offFn + 3072);
    __builtin_amdgcn_sched_barrier(0);

    // ---- kf = 1 ----
    COMPUTE_KF(bitsC0.y, bitsC1.y, BB0, BB1, BB2, BB3, ET1, ETN1);
    __builtin_amdgcn_sched_barrier(0);

    ET1.v = *(const h8*)(sE + offEn + 64);
    ETN1.v = *(const h8*)(sEN + offEn + 64);
    bitsC0 = bitsN0;
    bitsC1 = bitsN1;
    offF = offFn;
    offE = offEn;
    offB = offBn;
  }
#undef COMPUTE_KF

  // denominator partials per wave
#pragma unroll
  for (int rg = 0; rg < 2; ++rg) {
    float d = dsA[rg] + dsB[rg];
    d += __shfl_xor(d, 16, 64);
    d += __shfl_xor(d, 32, 64);
    if (quad == 0) denL[wave][rg * 16 + l16] = d;
  }

  // 2-phase epilogue: 16 rows per phase, 8-way cross-wave reduce.
  // 512 threads: row = tid>>5 (0..15), col pair = (tid&31)*2.
  const int erow = tid >> 5, ec0 = (tid & 31) << 1;
#pragma unroll
  for (int ph = 0; ph < 2; ++ph) {
    __syncthreads();
#pragma unroll
    for (int nb = 0; nb < 4; ++nb)
#pragma unroll
      for (int r = 0; r < 4; ++r)
        accL[wave][quad * 4 + r][nb * 16 + l16] = acc[ph][nb][r];
    __syncthreads();
    const int grow = ph * 16 + erow;
    float dn = 0.f;
#pragma unroll
    for (int w = 0; w < 8; ++w) dn += denL[w][grow];
    float inv = 1.0f / dn;  // self loop -> dn > 0
    f32x2 v = (f32x2){0.f, 0.f};
#pragma unroll
    for (int w = 0; w < 8; ++w) v += *(const f32x2*)&accL[w][erow][ec0];
    const f32x2 bv = *(const f32x2*)(bias + h * FF + ec0);
#pragma unroll
    for (int i = 0; i < 2; ++i) {
      float x = v[i] * inv + bv[i];
      v[i] = x > 0.f ? x : (__expf(x) - 1.0f);
    }
    *(f32x2*)(out + (size_t)(n0 + grow) * (HH * FF) + h * FF + ec0) = v;
  }
}

// ---------------------------------------------------------------- launch
extern "C" void kernel_launch(void* const* d_in, const int* in_sizes, int n_in,
                              void* d_out, int out_size, void* d_ws,
                              size_t ws_size, hipStream_t stream) {
  const float* X = (const float*)d_in[0];
  const int* A = (const int*)d_in[1];
  const float* W = (const float*)d_in[2];
  const float* b = (const float*)d_in[3];
  const float* a_self = (const float*)d_in[4];
  const float* a_neigh = (const float*)d_in[5];
  float* out = (float*)d_out;

  char* ws = (char*)d_ws;
  unsigned long long* Abits = (unsigned long long*)ws;        // 2 MB
  _Float16* feats_sw = (_Float16*)(ws + (2u << 20));          // 4 MB
  _Float16* es_h = (_Float16*)(ws + (6u << 20));              // 64 KB each
  _Float16* esn_h = (_Float16*)(ws + (6u << 20) + (64u << 10));
  _Float16* et_h = (_Float16*)(ws + (6u << 20) + (128u << 10));
  _Float16* etn_h = (_Float16*)(ws + (6u << 20) + (192u << 10));
  _Float16* Wsw = (_Float16*)(ws + (6u << 20) + (256u << 10));   // 128 KB
  _Float16* Xsw = (_Float16*)(ws + (6u << 20) + (384u << 10));   // 1 MB

  pack_kernel<<<NN + 66, 256, 0, stream>>>(A, W, X, Abits, Wsw, Xsw);
  feats_kernel<<<dim3(64, 8), 256, 0, stream>>>(Xsw, Wsw, a_self, a_neigh,
                                                feats_sw, es_h, esn_h, et_h,
                                                etn_h);
  attn_kernel<<<1024, 512, 0, stream>>>(Abits, feats_sw, es_h, esn_h, et_h,
                                        etn_h, b, out);
}

// Round 7
// 145.987 us; speedup vs baseline: 4.4545x; 4.4545x over previous
//
#include <hip/hip_runtime.h>
#include <cmath>

// GAT layer: N=4096 nodes, FIN=128, F=64 per head, H=8 heads.
//   k0: pack A -> 64-bit masks (ballot); swizzle W, X (fp32->f16) into
//       MFMA fragment order.
//   k1: feats = X @ W[h] via f16 MFMA; factored exps es/esn/et/etn (f16);
//       feats stored f16 in MFMA-B-swizzled order.
//   k2 v7: LDS-staged block-shared attention.
//       Rounds 2-5: four register-streaming inner loops all pinned ~46us;
//       occupancy 19->39% nearly flat => the wall is the per-wave private
//       L2 B-frag streaming, not intra-wave scheduling. Round 6: LB(512,8)
//       reg-capped to 32 VGPR -> spill catastrophe (554us). New structure:
//       128 rows/block, 8 waves x 16 rows (rg=1, one MFMA M-tile), all
//       64 cts per wave; B-frags + ET/ETN + bits staged to LDS ONCE per
//       block via global_load_lds (2 cts = 16KB per step, 3-buffer
//       rotation, counted vmcnt(3|2) + single s_barrier per step, never
//       vmcnt(0) in-loop). Waves own rows -> no cross-wave epilogue.

#define NN 4096
#define FIN 128
#define FF 64
#define HH 8

typedef _Float16 h2 __attribute__((ext_vector_type(2)));
typedef _Float16 h4 __attribute__((ext_vector_type(4)));
typedef _Float16 h8 __attribute__((ext_vector_type(8)));
typedef float f32x2 __attribute__((ext_vector_type(2)));
typedef float f32x4 __attribute__((ext_vector_type(4)));

union H8 {
  h8 v;
  h2 p[4];
};
union U2 {
  h2 h;
  unsigned u;
};

static __device__ __forceinline__ float dot2acc(h2 a, float c) {
#if __has_builtin(__builtin_amdgcn_fdot2)
  return __builtin_amdgcn_fdot2(a, (h2){(_Float16)1.f, (_Float16)1.f}, c,
                                false);
#else
  return c + (float)a[0] + (float)a[1];
#endif
}

// bits j, j+1 of w -> packed 16-bit masks {bit j ? 0xFFFF : 0, bit j+1 ...}
static __device__ __forceinline__ unsigned mask2(unsigned w, int j) {
#if __has_builtin(__builtin_amdgcn_sbfe) && __has_builtin(__builtin_amdgcn_perm)
  int lo = __builtin_amdgcn_sbfe((int)w, j, 1);  // 0 or 0xFFFFFFFF
  int hi = __builtin_amdgcn_sbfe((int)w, j + 1, 1);
  return __builtin_amdgcn_perm((unsigned)hi, (unsigned)lo, 0x05040100u);
#else
  int lo = ((int)(w << (31 - j))) >> 31;
  int hi = ((int)(w << (30 - j))) >> 31;
  return ((unsigned)lo & 0xFFFFu) | ((unsigned)hi << 16);
#endif
}

// async global->LDS, 16B per lane (dest = wave-uniform base + lane*16)
static __device__ __forceinline__ void gload16(const void* g, void* l) {
  __builtin_amdgcn_global_load_lds(
      (const __attribute__((address_space(1))) unsigned int*)g,
      (__attribute__((address_space(3))) unsigned int*)l, 16, 0, 0);
}

// ---------------------------------------------------------------- kernel 0
__global__ __launch_bounds__(256) void pack_kernel(
    const int* __restrict__ A, const float* __restrict__ W,
    const float* __restrict__ X, unsigned long long* __restrict__ bits,
    _Float16* __restrict__ Wsw, _Float16* __restrict__ Xsw) {
  const int b = blockIdx.x;
  const int tid = threadIdx.x;
  const int wave = tid >> 6, lane = tid & 63;
  if (b < NN) {
    __shared__ int ldsT[4][4][256];  // [wave][iter][col-within-group]
    const int* ar = A + (size_t)b * NN;
    int4 v[4];
#pragma unroll
    for (int it = 0; it < 4; ++it) {
      const int g = wave * 4 + it;  // 256-col group
      v[it] = *(const int4*)(ar + g * 256 + lane * 4);
    }
#pragma unroll
    for (int it = 0; it < 4; ++it) *(int4*)&ldsT[wave][it][lane * 4] = v[it];
    unsigned long long* br = bits + ((size_t)b << 6);
#pragma unroll
    for (int it = 0; it < 4; ++it) {
      const int g = wave * 4 + it;
      int w0 = ldsT[wave][it][0 * 64 + lane];
      int w1 = ldsT[wave][it][1 * 64 + lane];
      int w2 = ldsT[wave][it][2 * 64 + lane];
      int w3 = ldsT[wave][it][3 * 64 + lane];
      unsigned long long m0 = __ballot(w0 != 0);
      unsigned long long m1 = __ballot(w1 != 0);
      unsigned long long m2 = __ballot(w2 != 0);
      unsigned long long m3 = __ballot(w3 != 0);
      if (lane == 0) {
        ulonglong2 p0 = {m0, m1}, p1 = {m2, m3};
        *(ulonglong2*)(br + g * 4 + 0) = p0;
        *(ulonglong2*)(br + g * 4 + 2) = p1;
      }
    }
  } else if (b < NN + 2) {
    const int h0 = (b - NN) * 4;
    for (int h = h0; h < h0 + 4; ++h) {
      for (int c = tid; c < 1024; c += 256) {  // (kt, nb, lane)
        int ln = c & 63, nb = (c >> 6) & 3, kt = c >> 8;
        int f = nb * 16 + (ln & 15);
        int k0 = kt * 32 + (ln >> 4) * 8;
        h8 v;
#pragma unroll
        for (int j = 0; j < 8; ++j)
          v[j] = (_Float16)W[((size_t)(h * FIN) + k0 + j) * FF + f];
        *(h8*)(Wsw + ((size_t)(((h * 4 + kt) * 4 + nb) * 64 + ln)) * 8) = v;
      }
    }
  } else {
    const int tile = (b - NN - 2) * 4 + wave;  // 16-row tile, 0..255
    const int l16 = lane & 15, quad = lane >> 4;
    const float* xr = X + (size_t)(tile * 16 + l16) * FIN;
#pragma unroll
    for (int kt = 0; kt < 4; ++kt) {
      int k0 = kt * 32 + quad * 8;
      f32x4 x0 = *(const f32x4*)(xr + k0);
      f32x4 x1 = *(const f32x4*)(xr + k0 + 4);
      h8 v = {(_Float16)x0[0], (_Float16)x0[1], (_Float16)x0[2],
              (_Float16)x0[3], (_Float16)x1[0], (_Float16)x1[1],
              (_Float16)x1[2], (_Float16)x1[3]};
      *(h8*)(Xsw + ((size_t)((tile * 4 + kt) * 64 + lane)) * 8) = v;
    }
  }
}

// ---------------------------------------------------------------- kernel 1
__global__ __launch_bounds__(256) void feats_kernel(
    const _Float16* __restrict__ Xsw, const _Float16* __restrict__ Wsw,
    const float* __restrict__ a_self, const float* __restrict__ a_neigh,
    _Float16* __restrict__ feats_sw, _Float16* __restrict__ es_h,
    _Float16* __restrict__ esn_h, _Float16* __restrict__ et_h,
    _Float16* __restrict__ etn_h) {
  const int h = blockIdx.y;
  const int tid = threadIdx.x, wave = tid >> 6, lane = tid & 63;
  const int l16 = lane & 15, quad = lane >> 4;
  const int rt = blockIdx.x * 4 + wave;  // 16-row tile
  const int r0 = rt * 16;

  f32x4 acc[4];
#pragma unroll
  for (int nb = 0; nb < 4; ++nb) acc[nb] = (f32x4){0.f, 0.f, 0.f, 0.f};

  const _Float16* xp = Xsw + ((size_t)(rt * 4) * 64 + lane) * 8;
  const _Float16* wp = Wsw + ((size_t)(h * 16) * 64 + lane) * 8;
  h8 Af[4];
#pragma unroll
  for (int kt = 0; kt < 4; ++kt) Af[kt] = *(const h8*)(xp + kt * 512);
#pragma unroll
  for (int kt = 0; kt < 4; ++kt)
#pragma unroll
    for (int nb = 0; nb < 4; ++nb) {
      h8 Bf = *(const h8*)(wp + (kt * 4 + nb) * 512);
      acc[nb] = __builtin_amdgcn_mfma_f32_16x16x32_f16(Af[kt], Bf, acc[nb], 0, 0, 0);
    }

  // s_self/s_neigh dots (fp32) -> factored exponentials (f16)
  float as[4], an[4];
#pragma unroll
  for (int nb = 0; nb < 4; ++nb) {
    as[nb] = a_self[h * FF + nb * 16 + l16];
    an[nb] = a_neigh[h * FF + nb * 16 + l16];
  }
#pragma unroll
  for (int r = 0; r < 4; ++r) {
    float ps = acc[0][r] * as[0] + acc[1][r] * as[1] + acc[2][r] * as[2] +
               acc[3][r] * as[3];
    float pn = acc[0][r] * an[0] + acc[1][r] * an[1] + acc[2][r] * an[2] +
               acc[3][r] * an[3];
#pragma unroll
    for (int m = 1; m <= 8; m <<= 1) {
      ps += __shfl_xor(ps, m, 64);
      pn += __shfl_xor(pn, m, 64);
    }
    if (l16 == 0) {
      int node = h * NN + r0 + quad * 4 + r;
      es_h[node] = (_Float16)__expf(ps - 2.0f);
      esn_h[node] = (_Float16)__expf(0.2f * ps - 2.0f);
      et_h[node] = (_Float16)__expf(pn - 2.0f);
      etn_h[node] = (_Float16)__expf(0.2f * pn - 2.0f);
    }
  }

  // swizzled f16 store (MFMA B-fragment order). node = r0 + quad*4 + r.
  const int kb = r0 >> 5;
  const int quadA = ((r0 >> 4) & 1) * 2 + (quad >> 1);
  const int jbase = (quad & 1) << 2;
#pragma unroll
  for (int nb = 0; nb < 4; ++nb) {
    h4 v = {(_Float16)acc[nb][0], (_Float16)acc[nb][1], (_Float16)acc[nb][2],
            (_Float16)acc[nb][3]};
    size_t off = ((size_t)((h * 128 + kb) * 4 + nb) << 9) +
                 ((quadA * 16 + l16) << 3) + jbase;
    *(h4*)(feats_sw + off) = v;
  }
}

// ---------------------------------------------------------------- kernel 2
// grid 256 = rb*8 + h (head -> XCD). 128 rows/block, 512 thr = 8 waves,
// wave owns rows [n0+wave*16, +16) completely (rg=1), iterates all 64 cts
// in 32 two-ct steps. Per step: stage next 2 cts (feats 16KB + et/etn
// 512B + bits 2KB) into LDS buf[(s+1)%3] via global_load_lds; counted
// vmcnt(3|2) + one s_barrier; compute current from buf[s%3]. No
// register-destined global loads in the loop; no cross-wave epilogue.
// Per-step LDS slot: feats[16384] | et[1024] | etn[1024] | bits[2048].
__global__ __launch_bounds__(512, 2) void attn_kernel(
    const unsigned long long* __restrict__ Abits,
    const _Float16* __restrict__ feats_sw, const _Float16* __restrict__ es_h,
    const _Float16* __restrict__ esn_h, const _Float16* __restrict__ et_h,
    const _Float16* __restrict__ etn_h, const float* __restrict__ bias,
    float* __restrict__ out) {
  const int bid = blockIdx.x;
  const int h = bid & 7, n0 = (bid >> 3) << 7;  // 128 rows per block
  const int tid = threadIdx.x, wave = tid >> 6, lane = tid & 63;
  const int l16 = lane & 15, quad = lane >> 4;
  const int shq = quad << 3;

  __shared__ __align__(16) char smem[3 * 20480];  // 60 KB

  // per-row self exponentials (row = n0 + wave*16 + l16)
  const int myrow = n0 + (wave << 4) + l16;
  _Float16 e = es_h[h * NN + myrow];
  _Float16 en = esn_h[h * NN + myrow];
  const h2 esp = (h2){e, e};
  const h2 esnp = (h2){en, en};

  f32x4 acc[4];
#pragma unroll
  for (int nb = 0; nb < 4; ++nb) acc[nb] = (f32x4){0.f, 0.f, 0.f, 0.f};
  float dsA = 0.f, dsB = 0.f;

  // global bases
  const char* gF = (const char*)feats_sw + ((size_t)h << 19);  // h*512KB
  const char* gE = (const char*)et_h + (h << 13);
  const char* gEN = (const char*)etn_h + (h << 13);
  const char* gB = (const char*)Abits + ((size_t)n0 << 9);

  // stage step s (cts 2s, 2s+1) into buffer bw. Per wave: 2 feats gloads
  // (waves 0-3: +1 small gload) -> outstanding cluster = 3 | 2.
#define STAGE(s_, bw_)                                                        \
  do {                                                                        \
    char* L_ = smem + (bw_)*20480;                                            \
    const char* src_ = gF + ((size_t)(s_) << 14) + (wave << 11) + (lane << 4);\
    gload16(src_, L_ + (wave << 11) + (lane << 4));                           \
    gload16(src_ + 1024, L_ + (wave << 11) + 1024 + (lane << 4));             \
    if (wave == 0)                                                            \
      gload16(gE + ((s_) << 8) + (l16 << 4), L_ + 16384 + (lane << 4));       \
    if (wave == 1)                                                            \
      gload16(gEN + ((s_) << 8) + (l16 << 4), L_ + 17408 + (lane << 4));      \
    if (wave == 2)                                                            \
      gload16(gB + ((size_t)lane << 9) + ((s_) << 4),                         \
              L_ + 18432 + (lane << 4));                                      \
    if (wave == 3)                                                            \
      gload16(gB + ((size_t)(64 + lane) << 9) + ((s_) << 4),                  \
              L_ + 18432 + 1024 + (lane << 4));                               \
  } while (0)

  // prologue: stage steps 0 and 1
  STAGE(0, 0);
  STAGE(1, 1);

  for (int s = 0; s < 32; ++s) {
    const int bC = s % 3;
    // issue stage for s+2 worth? No: stage(s+1) already in flight from the
    // previous iteration (or prologue). Issue stage(s+2)'s predecessor:
    // we stage one step ahead each iteration.
    if (s < 30) {
      STAGE(s + 2, (s + 2) % 3);
      __builtin_amdgcn_sched_barrier(0);
      if (wave < 4)
        asm volatile("s_waitcnt vmcnt(6)" ::: "memory");  // stage(s) done;
      else                                                // s+1,s+2 in flight
        asm volatile("s_waitcnt vmcnt(4)" ::: "memory");
    } else if (s == 30) {
      __builtin_amdgcn_sched_barrier(0);
      if (wave < 4)
        asm volatile("s_waitcnt vmcnt(3)" ::: "memory");  // only s+1 in flight
      else
        asm volatile("s_waitcnt vmcnt(2)" ::: "memory");
    } else {
      __builtin_amdgcn_sched_barrier(0);
      asm volatile("s_waitcnt vmcnt(0)" ::: "memory");
    }
    __builtin_amdgcn_sched_barrier(0);
    __builtin_amdgcn_s_barrier();

    const char* L = smem + bC * 20480;
#pragma unroll
    for (int c = 0; c < 2; ++c) {
      unsigned long long myb = *(const unsigned long long*)(
          L + 18432 + (((wave << 4) + l16) << 4) + (c << 3));
#pragma unroll
      for (int kf = 0; kf < 2; ++kf) {
        H8 ET, ETN;
        ET.v = *(const h8*)(L + 16384 + (c << 7) + (kf << 6) + (quad << 4));
        ETN.v = *(const h8*)(L + 17408 + (c << 7) + (kf << 6) + (quad << 4));
        const char* fB = L + (c << 13) + (kf << 12) + (lane << 4);
        h8 B0 = *(const h8*)(fB);
        h8 B1 = *(const h8*)(fB + 1024);
        h8 B2 = *(const h8*)(fB + 2048);
        h8 B3 = *(const h8*)(fB + 3072);
        unsigned wsw = (unsigned)(myb >> (kf ? 32 : 0)) >> shq;
        H8 P;
#pragma unroll
        for (int p = 0; p < 4; ++p) {
          h2 a_ = esp * ET.p[p];
          h2 b_ = esnp * ETN.p[p];
          h2 r_ = __builtin_elementwise_max(a_, b_);
          U2 u_;
          u_.h = r_;
          u_.u &= mask2(wsw, 2 * p);
          P.p[p] = u_.h;
          if (p & 1)
            dsB = dot2acc(u_.h, dsB);
          else
            dsA = dot2acc(u_.h, dsA);
        }
        acc[0] = __builtin_amdgcn_mfma_f32_16x16x32_f16(P.v, B0, acc[0], 0, 0, 0);
        acc[1] = __builtin_amdgcn_mfma_f32_16x16x32_f16(P.v, B1, acc[1], 0, 0, 0);
        acc[2] = __builtin_amdgcn_mfma_f32_16x16x32_f16(P.v, B2, acc[2], 0, 0, 0);
        acc[3] = __builtin_amdgcn_mfma_f32_16x16x32_f16(P.v, B3, acc[3], 0, 0, 0);
      }
    }
  }
#undef STAGE

  // epilogue: fully per-wave (this wave owns its 16 rows)
  float den = dsA + dsB;
  den += __shfl_xor(den, 16, 64);
  den += __shfl_xor(den, 32, 64);  // all lanes: den for row l16
  const int orow = n0 + (wave << 4) + (quad << 2);
#pragma unroll
  for (int r = 0; r < 4; ++r) {
    float dr = __shfl(den, (quad << 2) + r, 64);  // den of row quad*4+r
    float inv = 1.0f / dr;                        // self loop -> dn > 0
#pragma unroll
    for (int nb = 0; nb < 4; ++nb) {
      float x = acc[nb][r] * inv + bias[h * FF + nb * 16 + l16];
      x = x > 0.f ? x : (__expf(x) - 1.0f);
      out[(size_t)(orow + r) * (HH * FF) + h * FF + nb * 16 + l16] = x;
    }
  }
}

// ---------------------------------------------------------------- launch
extern "C" void kernel_launch(void* const* d_in, const int* in_sizes, int n_in,
                              void* d_out, int out_size, void* d_ws,
                              size_t ws_size, hipStream_t stream) {
  const float* X = (const float*)d_in[0];
  const int* A = (const int*)d_in[1];
  const float* W = (const float*)d_in[2];
  const float* b = (const float*)d_in[3];
  const float* a_self = (const float*)d_in[4];
  const float* a_neigh = (const float*)d_in[5];
  float* out = (float*)d_out;

  char* ws = (char*)d_ws;
  unsigned long long* Abits = (unsigned long long*)ws;        // 2 MB
  _Float16* feats_sw = (_Float16*)(ws + (2u << 20));          // 4 MB
  _Float16* es_h = (_Float16*)(ws + (6u << 20));              // 64 KB each
  _Float16* esn_h = (_Float16*)(ws + (6u << 20) + (64u << 10));
  _Float16* et_h = (_Float16*)(ws + (6u << 20) + (128u << 10));
  _Float16* etn_h = (_Float16*)(ws + (6u << 20) + (192u << 10));
  _Float16* Wsw = (_Float16*)(ws + (6u << 20) + (256u << 10));   // 128 KB
  _Float16* Xsw = (_Float16*)(ws + (6u << 20) + (384u << 10));   // 1 MB

  pack_kernel<<<NN + 66, 256, 0, stream>>>(A, W, X, Abits, Wsw, Xsw);
  feats_kernel<<<dim3(64, 8), 256, 0, stream>>>(Xsw, Wsw, a_self, a_neigh,
                                                feats_sw, es_h, esn_h, et_h,
                                                etn_h);
  attn_kernel<<<256, 512, 0, stream>>>(Abits, feats_sw, es_h, esn_h, et_h,
                                       etn_h, b, out);
}

// Round 8
// 144.781 us; speedup vs baseline: 4.4917x; 1.0083x over previous
//
#include <hip/hip_runtime.h>
#include <cmath>

// GAT layer: N=4096 nodes, FIN=128, F=64 per head, H=8 heads.
//   k0: pack A -> 64-bit masks (ballot); swizzle W, X (fp32->f16) into
//       MFMA fragment order.
//   k1: feats = X @ W[h] via f16 MFMA; factored exps es/esn/et/etn (f16);
//       feats stored f16 in MFMA-B-swizzled order.
//   k2 v8: LDS-staged block-shared attention, column-split waves.
//       v7 (42us) proved the staged structure (bank-conflicts -> 0) but
//       ran 1 block/CU = 2 waves/SIMD (grid 256): chain latency exposed.
//       Row-tiles are exhausted (2048 tasks max) -> split COLUMNS:
//       64 rows/block, 8 waves = 4 row-tiles x 2 column-halves, each wave
//       1 ct/step; grid 512 -> 2 blocks/CU -> 4 waves/SIMD. STAGE moved
//       AFTER the barrier (closes v7's laggard-overwrite race; uniform
//       vmcnt 3|2). Pair (w, w^4) reduces via re-used staging LDS.

#define NN 4096
#define FIN 128
#define FF 64
#define HH 8

typedef _Float16 h2 __attribute__((ext_vector_type(2)));
typedef _Float16 h4 __attribute__((ext_vector_type(4)));
typedef _Float16 h8 __attribute__((ext_vector_type(8)));
typedef float f32x2 __attribute__((ext_vector_type(2)));
typedef float f32x4 __attribute__((ext_vector_type(4)));

union H8 {
  h8 v;
  h2 p[4];
};
union U2 {
  h2 h;
  unsigned u;
};

static __device__ __forceinline__ float dot2acc(h2 a, float c) {
#if __has_builtin(__builtin_amdgcn_fdot2)
  return __builtin_amdgcn_fdot2(a, (h2){(_Float16)1.f, (_Float16)1.f}, c,
                                false);
#else
  return c + (float)a[0] + (float)a[1];
#endif
}

// bits j, j+1 of w -> packed 16-bit masks {bit j ? 0xFFFF : 0, bit j+1 ...}
static __device__ __forceinline__ unsigned mask2(unsigned w, int j) {
#if __has_builtin(__builtin_amdgcn_sbfe) && __has_builtin(__builtin_amdgcn_perm)
  int lo = __builtin_amdgcn_sbfe((int)w, j, 1);  // 0 or 0xFFFFFFFF
  int hi = __builtin_amdgcn_sbfe((int)w, j + 1, 1);
  return __builtin_amdgcn_perm((unsigned)hi, (unsigned)lo, 0x05040100u);
#else
  int lo = ((int)(w << (31 - j))) >> 31;
  int hi = ((int)(w << (30 - j))) >> 31;
  return ((unsigned)lo & 0xFFFFu) | ((unsigned)hi << 16);
#endif
}

// async global->LDS, 16B per lane
static __device__ __forceinline__ void gload16(const void* g, void* l) {
  __builtin_amdgcn_global_load_lds(
      (const __attribute__((address_space(1))) unsigned int*)g,
      (__attribute__((address_space(3))) unsigned int*)l, 16, 0, 0);
}

// ---------------------------------------------------------------- kernel 0
__global__ __launch_bounds__(256) void pack_kernel(
    const int* __restrict__ A, const float* __restrict__ W,
    const float* __restrict__ X, unsigned long long* __restrict__ bits,
    _Float16* __restrict__ Wsw, _Float16* __restrict__ Xsw) {
  const int b = blockIdx.x;
  const int tid = threadIdx.x;
  const int wave = tid >> 6, lane = tid & 63;
  if (b < NN) {
    __shared__ int ldsT[4][4][256];  // [wave][iter][col-within-group]
    const int* ar = A + (size_t)b * NN;
    int4 v[4];
#pragma unroll
    for (int it = 0; it < 4; ++it) {
      const int g = wave * 4 + it;  // 256-col group
      v[it] = *(const int4*)(ar + g * 256 + lane * 4);
    }
#pragma unroll
    for (int it = 0; it < 4; ++it) *(int4*)&ldsT[wave][it][lane * 4] = v[it];
    unsigned long long* br = bits + ((size_t)b << 6);
#pragma unroll
    for (int it = 0; it < 4; ++it) {
      const int g = wave * 4 + it;
      int w0 = ldsT[wave][it][0 * 64 + lane];
      int w1 = ldsT[wave][it][1 * 64 + lane];
      int w2 = ldsT[wave][it][2 * 64 + lane];
      int w3 = ldsT[wave][it][3 * 64 + lane];
      unsigned long long m0 = __ballot(w0 != 0);
      unsigned long long m1 = __ballot(w1 != 0);
      unsigned long long m2 = __ballot(w2 != 0);
      unsigned long long m3 = __ballot(w3 != 0);
      if (lane == 0) {
        ulonglong2 p0 = {m0, m1}, p1 = {m2, m3};
        *(ulonglong2*)(br + g * 4 + 0) = p0;
        *(ulonglong2*)(br + g * 4 + 2) = p1;
      }
    }
  } else if (b < NN + 2) {
    const int h0 = (b - NN) * 4;
    for (int h = h0; h < h0 + 4; ++h) {
      for (int c = tid; c < 1024; c += 256) {  // (kt, nb, lane)
        int ln = c & 63, nb = (c >> 6) & 3, kt = c >> 8;
        int f = nb * 16 + (ln & 15);
        int k0 = kt * 32 + (ln >> 4) * 8;
        h8 v;
#pragma unroll
        for (int j = 0; j < 8; ++j)
          v[j] = (_Float16)W[((size_t)(h * FIN) + k0 + j) * FF + f];
        *(h8*)(Wsw + ((size_t)(((h * 4 + kt) * 4 + nb) * 64 + ln)) * 8) = v;
      }
    }
  } else {
    const int tile = (b - NN - 2) * 4 + wave;  // 16-row tile, 0..255
    const int l16 = lane & 15, quad = lane >> 4;
    const float* xr = X + (size_t)(tile * 16 + l16) * FIN;
#pragma unroll
    for (int kt = 0; kt < 4; ++kt) {
      int k0 = kt * 32 + quad * 8;
      f32x4 x0 = *(const f32x4*)(xr + k0);
      f32x4 x1 = *(const f32x4*)(xr + k0 + 4);
      h8 v = {(_Float16)x0[0], (_Float16)x0[1], (_Float16)x0[2],
              (_Float16)x0[3], (_Float16)x1[0], (_Float16)x1[1],
              (_Float16)x1[2], (_Float16)x1[3]};
      *(h8*)(Xsw + ((size_t)((tile * 4 + kt) * 64 + lane)) * 8) = v;
    }
  }
}

// ---------------------------------------------------------------- kernel 1
__global__ __launch_bounds__(256) void feats_kernel(
    const _Float16* __restrict__ Xsw, const _Float16* __restrict__ Wsw,
    const float* __restrict__ a_self, const float* __restrict__ a_neigh,
    _Float16* __restrict__ feats_sw, _Float16* __restrict__ es_h,
    _Float16* __restrict__ esn_h, _Float16* __restrict__ et_h,
    _Float16* __restrict__ etn_h) {
  const int h = blockIdx.y;
  const int tid = threadIdx.x, wave = tid >> 6, lane = tid & 63;
  const int l16 = lane & 15, quad = lane >> 4;
  const int rt = blockIdx.x * 4 + wave;  // 16-row tile
  const int r0 = rt * 16;

  f32x4 acc[4];
#pragma unroll
  for (int nb = 0; nb < 4; ++nb) acc[nb] = (f32x4){0.f, 0.f, 0.f, 0.f};

  const _Float16* xp = Xsw + ((size_t)(rt * 4) * 64 + lane) * 8;
  const _Float16* wp = Wsw + ((size_t)(h * 16) * 64 + lane) * 8;
  h8 Af[4];
#pragma unroll
  for (int kt = 0; kt < 4; ++kt) Af[kt] = *(const h8*)(xp + kt * 512);
#pragma unroll
  for (int kt = 0; kt < 4; ++kt)
#pragma unroll
    for (int nb = 0; nb < 4; ++nb) {
      h8 Bf = *(const h8*)(wp + (kt * 4 + nb) * 512);
      acc[nb] = __builtin_amdgcn_mfma_f32_16x16x32_f16(Af[kt], Bf, acc[nb], 0, 0, 0);
    }

  // s_self/s_neigh dots (fp32) -> factored exponentials (f16)
  float as[4], an[4];
#pragma unroll
  for (int nb = 0; nb < 4; ++nb) {
    as[nb] = a_self[h * FF + nb * 16 + l16];
    an[nb] = a_neigh[h * FF + nb * 16 + l16];
  }
#pragma unroll
  for (int r = 0; r < 4; ++r) {
    float ps = acc[0][r] * as[0] + acc[1][r] * as[1] + acc[2][r] * as[2] +
               acc[3][r] * as[3];
    float pn = acc[0][r] * an[0] + acc[1][r] * an[1] + acc[2][r] * an[2] +
               acc[3][r] * an[3];
#pragma unroll
    for (int m = 1; m <= 8; m <<= 1) {
      ps += __shfl_xor(ps, m, 64);
      pn += __shfl_xor(pn, m, 64);
    }
    if (l16 == 0) {
      int node = h * NN + r0 + quad * 4 + r;
      es_h[node] = (_Float16)__expf(ps - 2.0f);
      esn_h[node] = (_Float16)__expf(0.2f * ps - 2.0f);
      et_h[node] = (_Float16)__expf(pn - 2.0f);
      etn_h[node] = (_Float16)__expf(0.2f * pn - 2.0f);
    }
  }

  // swizzled f16 store (MFMA B-fragment order). node = r0 + quad*4 + r.
  const int kb = r0 >> 5;
  const int quadA = ((r0 >> 4) & 1) * 2 + (quad >> 1);
  const int jbase = (quad & 1) << 2;
#pragma unroll
  for (int nb = 0; nb < 4; ++nb) {
    h4 v = {(_Float16)acc[nb][0], (_Float16)acc[nb][1], (_Float16)acc[nb][2],
            (_Float16)acc[nb][3]};
    size_t off = ((size_t)((h * 128 + kb) * 4 + nb) << 9) +
                 ((quadA * 16 + l16) << 3) + jbase;
    *(h4*)(feats_sw + off) = v;
  }
}

// ---------------------------------------------------------------- kernel 2
// grid 512 = rb*8 + h (head -> XCD). 64 rows/block, 512 thr = 8 waves:
// wave = rtile (0..3, 16 rows) x half (column half of each staged step).
// Per step: stage(s+2) AFTER the barrier (race-free 3-buf rotation),
// counted vmcnt(3|2) (never 0 until the last step); each wave computes
// ct = 2s+half: 1 b64 bits + 2kf x {ET,ETN,4 B-frags} ds_reads + 8 MFMA.
// LDS slot: feats[16384] | et[1024] | etn[1024] | bits[1024] = 19456 x3
// = 58.4 KB -> 2 blocks/CU -> 4 waves/SIMD. Pair (w, w^4) reduces acc
// and den via re-used staging LDS in the epilogue.
__global__ __launch_bounds__(512, 4) void attn_kernel(
    const unsigned long long* __restrict__ Abits,
    const _Float16* __restrict__ feats_sw, const _Float16* __restrict__ es_h,
    const _Float16* __restrict__ esn_h, const _Float16* __restrict__ et_h,
    const _Float16* __restrict__ etn_h, const float* __restrict__ bias,
    float* __restrict__ out) {
  const int bid = blockIdx.x;
  const int h = bid & 7, n0 = (bid >> 3) << 6;  // 64 rows per block
  const int tid = threadIdx.x, wave = tid >> 6, lane = tid & 63;
  const int l16 = lane & 15, quad = lane >> 4;
  const int shq = quad << 3;
  const int rtile = wave & 3, half = wave >> 2;

  __shared__ __align__(16) char smem[3 * 19456];  // 58.4 KB

  // per-row self exponentials (row = n0 + rtile*16 + l16)
  const int myrow = n0 + (rtile << 4) + l16;
  _Float16 e = es_h[h * NN + myrow];
  _Float16 en = esn_h[h * NN + myrow];
  const h2 esp = (h2){e, e};
  const h2 esnp = (h2){en, en};

  f32x4 acc[4];
#pragma unroll
  for (int nb = 0; nb < 4; ++nb) acc[nb] = (f32x4){0.f, 0.f, 0.f, 0.f};
  float dsA = 0.f, dsB = 0.f;

  // global bases
  const char* gF = (const char*)feats_sw + ((size_t)h << 19);  // h*512KB
  const char* gE = (const char*)et_h + (h << 13);
  const char* gEN = (const char*)etn_h + (h << 13);
  const char* gB = (const char*)Abits + ((size_t)n0 << 9);

  // stage step s (cts 2s, 2s+1): feats 16KB (8 waves x 2 gloads) +
  // et/etn 256B (waves 0/1, dup x4 harmless) + bits 1KB (wave 2).
  // outstanding per stage: waves 0-2: 3, waves 3-7: 2.
#define STAGE(s_, bw_)                                                         \
  do {                                                                         \
    char* L_ = smem + (bw_)*19456;                                             \
    const char* src_ = gF + ((size_t)(s_) << 14) + (wave << 11) + (lane << 4); \
    gload16(src_, L_ + (wave << 11) + (lane << 4));                            \
    gload16(src_ + 1024, L_ + (wave << 11) + 1024 + (lane << 4));              \
    if (wave == 0)                                                             \
      gload16(gE + ((s_) << 8) + (l16 << 4), L_ + 16384 + (lane << 4));        \
    if (wave == 1)                                                             \
      gload16(gEN + ((s_) << 8) + (l16 << 4), L_ + 17408 + (lane << 4));       \
    if (wave == 2)                                                             \
      gload16(gB + ((size_t)lane << 9) + ((s_) << 4), L_ + 18432 + (lane << 4)); \
  } while (0)

  // prologue: stage steps 0 and 1
  STAGE(0, 0);
  STAGE(1, 1);

  for (int s = 0; s < 32; ++s) {
    __builtin_amdgcn_sched_barrier(0);
    if (s < 31) {
      if (wave < 3)
        asm volatile("s_waitcnt vmcnt(3)" ::: "memory");  // stage(s) done,
      else                                                // stage(s+1) flying
        asm volatile("s_waitcnt vmcnt(2)" ::: "memory");
    } else {
      asm volatile("s_waitcnt vmcnt(0)" ::: "memory");
    }
    __builtin_amdgcn_sched_barrier(0);
    __builtin_amdgcn_s_barrier();
    // stage(s+2): safe here — all waves are past compute(s-1), and buffer
    // (s+2)%3 != s%3 (the only buffer read in this barrier interval).
    if (s < 30) STAGE(s + 2, (s + 2) % 3);

    const char* L = smem + (s % 3) * 19456;
    // adjacency bits for my 16 rows, my column half (8B)
    unsigned long long myb = *(const unsigned long long*)(
        L + 18432 + (((rtile << 4) + l16) << 4) + (half << 3));
#pragma unroll
    for (int kf = 0; kf < 2; ++kf) {
      H8 ET, ETN;
      ET.v = *(const h8*)(L + 16384 + (half << 7) + (kf << 6) + (quad << 4));
      ETN.v = *(const h8*)(L + 17408 + (half << 7) + (kf << 6) + (quad << 4));
      const char* fB = L + (half << 13) + (kf << 12) + (lane << 4);
      h8 B0 = *(const h8*)(fB);
      h8 B1 = *(const h8*)(fB + 1024);
      h8 B2 = *(const h8*)(fB + 2048);
      h8 B3 = *(const h8*)(fB + 3072);
      unsigned wsw = (unsigned)(myb >> (kf ? 32 : 0)) >> shq;
      H8 P;
#pragma unroll
      for (int p = 0; p < 4; ++p) {
        h2 a_ = esp * ET.p[p];
        h2 b_ = esnp * ETN.p[p];
        h2 r_ = __builtin_elementwise_max(a_, b_);
        U2 u_;
        u_.h = r_;
        u_.u &= mask2(wsw, 2 * p);
        P.p[p] = u_.h;
        if (p & 1)
          dsB = dot2acc(u_.h, dsB);
        else
          dsA = dot2acc(u_.h, dsA);
      }
      acc[0] = __builtin_amdgcn_mfma_f32_16x16x32_f16(P.v, B0, acc[0], 0, 0, 0);
      acc[1] = __builtin_amdgcn_mfma_f32_16x16x32_f16(P.v, B1, acc[1], 0, 0, 0);
      acc[2] = __builtin_amdgcn_mfma_f32_16x16x32_f16(P.v, B2, acc[2], 0, 0, 0);
      acc[3] = __builtin_amdgcn_mfma_f32_16x16x32_f16(P.v, B3, acc[3], 0, 0, 0);
    }
  }
#undef STAGE

  // den partial for my rows over my column half; all lanes: row l16
  float den = dsA + dsB;
  den += __shfl_xor(den, 16, 64);
  den += __shfl_xor(den, 32, 64);

  // pair (rtile, half=0) + (rtile, half=1) reduce via re-used staging LDS
  float(*accL)[16][68] = (float(*)[16][68])smem;           // 17408 B
  float(*denL)[16] = (float(*)[16])(smem + 4 * 16 * 68 * 4);  // 256 B
  __syncthreads();  // all compute reads of smem done
  if (half == 1) {
#pragma unroll
    for (int nb = 0; nb < 4; ++nb)
#pragma unroll
      for (int r = 0; r < 4; ++r)
        accL[rtile][quad * 4 + r][nb * 16 + l16] = acc[nb][r];
    if (quad == 0) denL[rtile][l16] = den;
  }
  __syncthreads();
  if (half == 0) {
    float dtot = den + denL[rtile][l16];  // per-lane: den of row l16
    const int orow = n0 + (rtile << 4) + (quad << 2);
#pragma unroll
    for (int r = 0; r < 4; ++r) {
      float dr = __shfl(dtot, (quad << 2) + r, 64);
      float inv = 1.0f / dr;  // self loop -> dr > 0
#pragma unroll
      for (int nb = 0; nb < 4; ++nb) {
        float x = (acc[nb][r] + accL[rtile][quad * 4 + r][nb * 16 + l16]) * inv +
                  bias[h * FF + nb * 16 + l16];
        x = x > 0.f ? x : (__expf(x) - 1.0f);
        out[(size_t)(orow + r) * (HH * FF) + h * FF + nb * 16 + l16] = x;
      }
    }
  }
}

// ---------------------------------------------------------------- launch
extern "C" void kernel_launch(void* const* d_in, const int* in_sizes, int n_in,
                              void* d_out, int out_size, void* d_ws,
                              size_t ws_size, hipStream_t stream) {
  const float* X = (const float*)d_in[0];
  const int* A = (const int*)d_in[1];
  const float* W = (const float*)d_in[2];
  const float* b = (const float*)d_in[3];
  const float* a_self = (const float*)d_in[4];
  const float* a_neigh = (const float*)d_in[5];
  float* out = (float*)d_out;

  char* ws = (char*)d_ws;
  unsigned long long* Abits = (unsigned long long*)ws;        // 2 MB
  _Float16* feats_sw = (_Float16*)(ws + (2u << 20));          // 4 MB
  _Float16* es_h = (_Float16*)(ws + (6u << 20));              // 64 KB each
  _Float16* esn_h = (_Float16*)(ws + (6u << 20) + (64u << 10));
  _Float16* et_h = (_Float16*)(ws + (6u << 20) + (128u << 10));
  _Float16* etn_h = (_Float16*)(ws + (6u << 20) + (192u << 10));
  _Float16* Wsw = (_Float16*)(ws + (6u << 20) + (256u << 10));   // 128 KB
  _Float16* Xsw = (_Float16*)(ws + (6u << 20) + (384u << 10));   // 1 MB

  pack_kernel<<<NN + 66, 256, 0, stream>>>(A, W, X, Abits, Wsw, Xsw);
  feats_kernel<<<dim3(64, 8), 256, 0, stream>>>(Xsw, Wsw, a_self, a_neigh,
                                                feats_sw, es_h, esn_h, et_h,
                                                etn_h);
  attn_kernel<<<512, 512, 0, stream>>>(Abits, feats_sw, es_h, esn_h, et_h,
                                       etn_h, b, out);
}

// Round 9
// 143.862 us; speedup vs baseline: 4.5203x; 1.0064x over previous
//
#include <hip/hip_runtime.h>
#include <cmath>

// GAT layer: N=4096 nodes, FIN=128, F=64 per head, H=8 heads.
//   k0: pack A -> 64-bit masks (ballot); swizzle W, X (fp32->f16) into
//       MFMA fragment order.
//   k1: feats = X @ W[h] via f16 MFMA; factored exps es/esn/et/etn (f16);
//       feats stored f16 in MFMA-B-swizzled order.
//   k2 v9: LDS-staged attention, rg=2 (wave owns 2 row-tiles).
//       v8 diagnosis: per-CU LDS READ bandwidth is the wall (6400 b128 x
//       12cy = 32us = measured 41.7us kernel; TLP doublings moved ~1us).
//       rg=1 meant each B-frag read fed exactly 1 MFMA. v9: wave =
//       (kf, ct-in-step, row-half): 2 row-tiles per wave -> same B/ET
//       reads feed 8 MFMAs -> LDS reads halve (~18us). Denominator via
//       5th MFMA with ones-B (row sums in acc) -> -8 v_dot2/step off the
//       VALU pipe. Same 3-buf rotation, stage-after-barrier, counted
//       vmcnt(3|2). LB(512,4): ~100 VGPR, 2 blocks/CU, 4 waves/SIMD.

#define NN 4096
#define FIN 128
#define FF 64
#define HH 8

typedef _Float16 h2 __attribute__((ext_vector_type(2)));
typedef _Float16 h4 __attribute__((ext_vector_type(4)));
typedef _Float16 h8 __attribute__((ext_vector_type(8)));
typedef float f32x2 __attribute__((ext_vector_type(2)));
typedef float f32x4 __attribute__((ext_vector_type(4)));

union H8 {
  h8 v;
  h2 p[4];
};
union U2 {
  h2 h;
  unsigned u;
};

// bits j, j+1 of w -> packed 16-bit masks {bit j ? 0xFFFF : 0, bit j+1 ...}
static __device__ __forceinline__ unsigned mask2(unsigned w, int j) {
#if __has_builtin(__builtin_amdgcn_sbfe) && __has_builtin(__builtin_amdgcn_perm)
  int lo = __builtin_amdgcn_sbfe((int)w, j, 1);  // 0 or 0xFFFFFFFF
  int hi = __builtin_amdgcn_sbfe((int)w, j + 1, 1);
  return __builtin_amdgcn_perm((unsigned)hi, (unsigned)lo, 0x05040100u);
#else
  int lo = ((int)(w << (31 - j))) >> 31;
  int hi = ((int)(w << (30 - j))) >> 31;
  return ((unsigned)lo & 0xFFFFu) | ((unsigned)hi << 16);
#endif
}

// async global->LDS, 16B per lane
static __device__ __forceinline__ void gload16(const void* g, void* l) {
  __builtin_amdgcn_global_load_lds(
      (const __attribute__((address_space(1))) unsigned int*)g,
      (__attribute__((address_space(3))) unsigned int*)l, 16, 0, 0);
}

// ---------------------------------------------------------------- kernel 0
__global__ __launch_bounds__(256) void pack_kernel(
    const int* __restrict__ A, const float* __restrict__ W,
    const float* __restrict__ X, unsigned long long* __restrict__ bits,
    _Float16* __restrict__ Wsw, _Float16* __restrict__ Xsw) {
  const int b = blockIdx.x;
  const int tid = threadIdx.x;
  const int wave = tid >> 6, lane = tid & 63;
  if (b < NN) {
    __shared__ int ldsT[4][4][256];  // [wave][iter][col-within-group]
    const int* ar = A + (size_t)b * NN;
    int4 v[4];
#pragma unroll
    for (int it = 0; it < 4; ++it) {
      const int g = wave * 4 + it;  // 256-col group
      v[it] = *(const int4*)(ar + g * 256 + lane * 4);
    }
#pragma unroll
    for (int it = 0; it < 4; ++it) *(int4*)&ldsT[wave][it][lane * 4] = v[it];
    unsigned long long* br = bits + ((size_t)b << 6);
#pragma unroll
    for (int it = 0; it < 4; ++it) {
      const int g = wave * 4 + it;
      int w0 = ldsT[wave][it][0 * 64 + lane];
      int w1 = ldsT[wave][it][1 * 64 + lane];
      int w2 = ldsT[wave][it][2 * 64 + lane];
      int w3 = ldsT[wave][it][3 * 64 + lane];
      unsigned long long m0 = __ballot(w0 != 0);
      unsigned long long m1 = __ballot(w1 != 0);
      unsigned long long m2 = __ballot(w2 != 0);
      unsigned long long m3 = __ballot(w3 != 0);
      if (lane == 0) {
        ulonglong2 p0 = {m0, m1}, p1 = {m2, m3};
        *(ulonglong2*)(br + g * 4 + 0) = p0;
        *(ulonglong2*)(br + g * 4 + 2) = p1;
      }
    }
  } else if (b < NN + 2) {
    const int h0 = (b - NN) * 4;
    for (int h = h0; h < h0 + 4; ++h) {
      for (int c = tid; c < 1024; c += 256) {  // (kt, nb, lane)
        int ln = c & 63, nb = (c >> 6) & 3, kt = c >> 8;
        int f = nb * 16 + (ln & 15);
        int k0 = kt * 32 + (ln >> 4) * 8;
        h8 v;
#pragma unroll
        for (int j = 0; j < 8; ++j)
          v[j] = (_Float16)W[((size_t)(h * FIN) + k0 + j) * FF + f];
        *(h8*)(Wsw + ((size_t)(((h * 4 + kt) * 4 + nb) * 64 + ln)) * 8) = v;
      }
    }
  } else {
    const int tile = (b - NN - 2) * 4 + wave;  // 16-row tile, 0..255
    const int l16 = lane & 15, quad = lane >> 4;
    const float* xr = X + (size_t)(tile * 16 + l16) * FIN;
#pragma unroll
    for (int kt = 0; kt < 4; ++kt) {
      int k0 = kt * 32 + quad * 8;
      f32x4 x0 = *(const f32x4*)(xr + k0);
      f32x4 x1 = *(const f32x4*)(xr + k0 + 4);
      h8 v = {(_Float16)x0[0], (_Float16)x0[1], (_Float16)x0[2],
              (_Float16)x0[3], (_Float16)x1[0], (_Float16)x1[1],
              (_Float16)x1[2], (_Float16)x1[3]};
      *(h8*)(Xsw + ((size_t)((tile * 4 + kt) * 64 + lane)) * 8) = v;
    }
  }
}

// ---------------------------------------------------------------- kernel 1
__global__ __launch_bounds__(256) void feats_kernel(
    const _Float16* __restrict__ Xsw, const _Float16* __restrict__ Wsw,
    const float* __restrict__ a_self, const float* __restrict__ a_neigh,
    _Float16* __restrict__ feats_sw, _Float16* __restrict__ es_h,
    _Float16* __restrict__ esn_h, _Float16* __restrict__ et_h,
    _Float16* __restrict__ etn_h) {
  const int h = blockIdx.y;
  const int tid = threadIdx.x, wave = tid >> 6, lane = tid & 63;
  const int l16 = lane & 15, quad = lane >> 4;
  const int rt = blockIdx.x * 4 + wave;  // 16-row tile
  const int r0 = rt * 16;

  f32x4 acc[4];
#pragma unroll
  for (int nb = 0; nb < 4; ++nb) acc[nb] = (f32x4){0.f, 0.f, 0.f, 0.f};

  const _Float16* xp = Xsw + ((size_t)(rt * 4) * 64 + lane) * 8;
  const _Float16* wp = Wsw + ((size_t)(h * 16) * 64 + lane) * 8;
  h8 Af[4];
#pragma unroll
  for (int kt = 0; kt < 4; ++kt) Af[kt] = *(const h8*)(xp + kt * 512);
#pragma unroll
  for (int kt = 0; kt < 4; ++kt)
#pragma unroll
    for (int nb = 0; nb < 4; ++nb) {
      h8 Bf = *(const h8*)(wp + (kt * 4 + nb) * 512);
      acc[nb] = __builtin_amdgcn_mfma_f32_16x16x32_f16(Af[kt], Bf, acc[nb], 0, 0, 0);
    }

  // s_self/s_neigh dots (fp32) -> factored exponentials (f16)
  float as[4], an[4];
#pragma unroll
  for (int nb = 0; nb < 4; ++nb) {
    as[nb] = a_self[h * FF + nb * 16 + l16];
    an[nb] = a_neigh[h * FF + nb * 16 + l16];
  }
#pragma unroll
  for (int r = 0; r < 4; ++r) {
    float ps = acc[0][r] * as[0] + acc[1][r] * as[1] + acc[2][r] * as[2] +
               acc[3][r] * as[3];
    float pn = acc[0][r] * an[0] + acc[1][r] * an[1] + acc[2][r] * an[2] +
               acc[3][r] * an[3];
#pragma unroll
    for (int m = 1; m <= 8; m <<= 1) {
      ps += __shfl_xor(ps, m, 64);
      pn += __shfl_xor(pn, m, 64);
    }
    if (l16 == 0) {
      int node = h * NN + r0 + quad * 4 + r;
      es_h[node] = (_Float16)__expf(ps - 2.0f);
      esn_h[node] = (_Float16)__expf(0.2f * ps - 2.0f);
      et_h[node] = (_Float16)__expf(pn - 2.0f);
      etn_h[node] = (_Float16)__expf(0.2f * pn - 2.0f);
    }
  }

  // swizzled f16 store (MFMA B-fragment order). node = r0 + quad*4 + r.
  const int kb = r0 >> 5;
  const int quadA = ((r0 >> 4) & 1) * 2 + (quad >> 1);
  const int jbase = (quad & 1) << 2;
#pragma unroll
  for (int nb = 0; nb < 4; ++nb) {
    h4 v = {(_Float16)acc[nb][0], (_Float16)acc[nb][1], (_Float16)acc[nb][2],
            (_Float16)acc[nb][3]};
    size_t off = ((size_t)((h * 128 + kb) * 4 + nb) << 9) +
                 ((quadA * 16 + l16) << 3) + jbase;
    *(h4*)(feats_sw + off) = v;
  }
}

// ---------------------------------------------------------------- kernel 2
// grid 512 = rb*8 + h (head -> XCD). 64 rows/block, 512 thr = 8 waves:
// wave = kfw*4 + ctw*2 + rh; wave computes (ct=2s+ctw, kf=kfw) for the
// 32 rows of half rh (2 row-tiles -> 8+2 MFMA per step off 4 B-frag +
// 2 ET/ETN LDS reads). Denominator via mfma(P, ones): row sums in accd.
// Stage(s+2) after barrier (race-free 3-buf), counted vmcnt(3|2).
// LDS slot: feats[16384] | et[1024] | etn[1024] | bits[1024] = 19456 x3
// = 58.4 KB -> 2 blocks/CU -> 4 waves/SIMD. Epilogue: 2 phases (rt),
// 4-way cross-wave reduce via re-used staging LDS.
__global__ __launch_bounds__(512, 4) void attn_kernel(
    const unsigned long long* __restrict__ Abits,
    const _Float16* __restrict__ feats_sw, const _Float16* __restrict__ es_h,
    const _Float16* __restrict__ esn_h, const _Float16* __restrict__ et_h,
    const _Float16* __restrict__ etn_h, const float* __restrict__ bias,
    float* __restrict__ out) {
  const int bid = blockIdx.x;
  const int h = bid & 7, n0 = (bid >> 3) << 6;  // 64 rows per block
  const int tid = threadIdx.x, wave = tid >> 6, lane = tid & 63;
  const int l16 = lane & 15, quad = lane >> 4;
  const int shq = quad << 3;
  const int rh = wave & 1, ctw = (wave >> 1) & 1, kfw = wave >> 2;

  __shared__ __align__(16) char smem[3 * 19456];  // 58.4 KB

  // per-row self exponentials for my 2 row-tiles (rows rh*32 + rt*16 + l16)
  h2 esp[2], esnp[2];
#pragma unroll
  for (int rt = 0; rt < 2; ++rt) {
    const int myrow = n0 + (rh << 5) + (rt << 4) + l16;
    _Float16 e = es_h[h * NN + myrow];
    _Float16 en = esn_h[h * NN + myrow];
    esp[rt] = (h2){e, e};
    esnp[rt] = (h2){en, en};
  }

  f32x4 acc[2][4], accd[2];
#pragma unroll
  for (int rt = 0; rt < 2; ++rt) {
    accd[rt] = (f32x4){0.f, 0.f, 0.f, 0.f};
#pragma unroll
    for (int nb = 0; nb < 4; ++nb) acc[rt][nb] = (f32x4){0.f, 0.f, 0.f, 0.f};
  }
  const h8 ONES = {(_Float16)1.f, (_Float16)1.f, (_Float16)1.f, (_Float16)1.f,
                   (_Float16)1.f, (_Float16)1.f, (_Float16)1.f, (_Float16)1.f};

  // global bases
  const char* gF = (const char*)feats_sw + ((size_t)h << 19);  // h*512KB
  const char* gE = (const char*)et_h + (h << 13);
  const char* gEN = (const char*)etn_h + (h << 13);
  const char* gB = (const char*)Abits + ((size_t)n0 << 9);

  // stage step s (cts 2s, 2s+1): feats 16KB (8 waves x 2 gloads) +
  // et/etn 256B (waves 0/1) + bits 1KB (wave 2: 64 rows x 16B).
#define STAGE(s_, bw_)                                                         \
  do {                                                                         \
    char* L_ = smem + (bw_)*19456;                                             \
    const char* src_ = gF + ((size_t)(s_) << 14) + (wave << 11) + (lane << 4); \
    gload16(src_, L_ + (wave << 11) + (lane << 4));                            \
    gload16(src_ + 1024, L_ + (wave << 11) + 1024 + (lane << 4));              \
    if (wave == 0)                                                             \
      gload16(gE + ((s_) << 8) + (l16 << 4), L_ + 16384 + (lane << 4));        \
    if (wave == 1)                                                             \
      gload16(gEN + ((s_) << 8) + (l16 << 4), L_ + 17408 + (lane << 4));       \
    if (wave == 2)                                                             \
      gload16(gB + ((size_t)lane << 9) + ((s_) << 4), L_ + 18432 + (lane << 4)); \
  } while (0)

  // prologue: stage steps 0 and 1
  STAGE(0, 0);
  STAGE(1, 1);

  for (int s = 0; s < 32; ++s) {
    __builtin_amdgcn_sched_barrier(0);
    if (s < 31) {
      if (wave < 3)
        asm volatile("s_waitcnt vmcnt(3)" ::: "memory");  // stage(s) done,
      else                                                // stage(s+1) flying
        asm volatile("s_waitcnt vmcnt(2)" ::: "memory");
    } else {
      asm volatile("s_waitcnt vmcnt(0)" ::: "memory");
    }
    __builtin_amdgcn_sched_barrier(0);
    __builtin_amdgcn_s_barrier();
    // stage(s+2): safe — buffer (s+2)%3 != s%3, and all waves passed the
    // barrier ending interval s-1 (which read (s+2)%3 == (s-1)%3).
    if (s < 30) STAGE(s + 2, (s + 2) % 3);

    const char* L = smem + (s % 3) * 19456;
    // adjacency bits: my 2 row-tiles, my ct (8B each)
    unsigned long long mb0 = *(const unsigned long long*)(
        L + 18432 + (((rh << 5) + l16) << 4) + (ctw << 3));
    unsigned long long mb1 = *(const unsigned long long*)(
        L + 18432 + (((rh << 5) + 16 + l16) << 4) + (ctw << 3));
    // column terms for my (ct, kf): shared across both row-tiles
    H8 ET, ETN;
    ET.v = *(const h8*)(L + 16384 + (ctw << 7) + (kfw << 6) + (quad << 4));
    ETN.v = *(const h8*)(L + 17408 + (ctw << 7) + (kfw << 6) + (quad << 4));
    const char* fB = L + (ctw << 13) + (kfw << 12) + (lane << 4);
    h8 B0 = *(const h8*)(fB);
    h8 B1 = *(const h8*)(fB + 1024);
    h8 B2 = *(const h8*)(fB + 2048);
    h8 B3 = *(const h8*)(fB + 3072);

#pragma unroll
    for (int rt = 0; rt < 2; ++rt) {
      unsigned long long myb = rt ? mb1 : mb0;
      unsigned wsw = (unsigned)(myb >> (kfw ? 32 : 0)) >> shq;
      H8 P;
#pragma unroll
      for (int p = 0; p < 4; ++p) {
        h2 a_ = esp[rt] * ET.p[p];
        h2 b_ = esnp[rt] * ETN.p[p];
        h2 r_ = __builtin_elementwise_max(a_, b_);
        U2 u_;
        u_.h = r_;
        u_.u &= mask2(wsw, 2 * p);
        P.p[p] = u_.h;
      }
      acc[rt][0] =
          __builtin_amdgcn_mfma_f32_16x16x32_f16(P.v, B0, acc[rt][0], 0, 0, 0);
      acc[rt][1] =
          __builtin_amdgcn_mfma_f32_16x16x32_f16(P.v, B1, acc[rt][1], 0, 0, 0);
      acc[rt][2] =
          __builtin_amdgcn_mfma_f32_16x16x32_f16(P.v, B2, acc[rt][2], 0, 0, 0);
      acc[rt][3] =
          __builtin_amdgcn_mfma_f32_16x16x32_f16(P.v, B3, acc[rt][3], 0, 0, 0);
      accd[rt] =
          __builtin_amdgcn_mfma_f32_16x16x32_f16(P.v, ONES, accd[rt], 0, 0, 0);
    }
  }
#undef STAGE

  // epilogue: 2 phases (rt); 4-way cross-wave reduce via re-used LDS.
  // accd[rt][r]: every lane holds den(row quad*4+r) (all cols of ones-MFMA
  // output are the row sum).
  float(*accL)[16][68] = (float(*)[16][68])smem;            // 34,816 B
  float* denL = (float*)(smem + 8 * 16 * 68 * 4);           // 512 B
  const int erow = tid >> 4;            // 0..31
  const int rh_o = erow >> 4, r16 = erow & 15;
  const int ec0 = (tid & 15) << 2;
#pragma unroll
  for (int rt = 0; rt < 2; ++rt) {
    __syncthreads();
#pragma unroll
    for (int nb = 0; nb < 4; ++nb)
#pragma unroll
      for (int r = 0; r < 4; ++r)
        accL[wave][quad * 4 + r][nb * 16 + l16] = acc[rt][nb][r];
    if (l16 == 0) {
#pragma unroll
      for (int r = 0; r < 4; ++r) denL[wave * 16 + quad * 4 + r] = accd[rt][r];
    }
    __syncthreads();
    f32x4 v = (f32x4){0.f, 0.f, 0.f, 0.f};
    float dn = 0.f;
#pragma unroll
    for (int cw = 0; cw < 4; ++cw) {
      const int w = rh_o + ((cw & 1) << 1) + ((cw >> 1) << 2);
      v += *(const f32x4*)&accL[w][r16][ec0];
      dn += denL[w * 16 + r16];
    }
    float inv = 1.0f / dn;  // self loop -> dn > 0
    const f32x4 bv = *(const f32x4*)(bias + h * FF + ec0);
#pragma unroll
    for (int i = 0; i < 4; ++i) {
      float x = v[i] * inv + bv[i];
      v[i] = x > 0.f ? x : (__expf(x) - 1.0f);
    }
    *(f32x4*)(out + (size_t)(n0 + (rh_o << 5) + (rt << 4) + r16) * (HH * FF) +
              h * FF + ec0) = v;
  }
}

// ---------------------------------------------------------------- launch
extern "C" void kernel_launch(void* const* d_in, const int* in_sizes, int n_in,
                              void* d_out, int out_size, void* d_ws,
                              size_t ws_size, hipStream_t stream) {
  const float* X = (const float*)d_in[0];
  const int* A = (const int*)d_in[1];
  const float* W = (const float*)d_in[2];
  const float* b = (const float*)d_in[3];
  const float* a_self = (const float*)d_in[4];
  const float* a_neigh = (const float*)d_in[5];
  float* out = (float*)d_out;

  char* ws = (char*)d_ws;
  unsigned long long* Abits = (unsigned long long*)ws;        // 2 MB
  _Float16* feats_sw = (_Float16*)(ws + (2u << 20));          // 4 MB
  _Float16* es_h = (_Float16*)(ws + (6u << 20));              // 64 KB each
  _Float16* esn_h = (_Float16*)(ws + (6u << 20) + (64u << 10));
  _Float16* et_h = (_Float16*)(ws + (6u << 20) + (128u << 10));
  _Float16* etn_h = (_Float16*)(ws + (6u << 20) + (192u << 10));
  _Float16* Wsw = (_Float16*)(ws + (6u << 20) + (256u << 10));   // 128 KB
  _Float16* Xsw = (_Float16*)(ws + (6u << 20) + (384u << 10));   // 1 MB

  pack_kernel<<<NN + 66, 256, 0, stream>>>(A, W, X, Abits, Wsw, Xsw);
  feats_kernel<<<dim3(64, 8), 256, 0, stream>>>(Xsw, Wsw, a_self, a_neigh,
                                                feats_sw, es_h, esn_h, et_h,
                                                etn_h);
  attn_kernel<<<512, 512, 0, stream>>>(Abits, feats_sw, es_h, esn_h, et_h,
                                       etn_h, b, out);
}